// Round 3
// baseline (242.051 us; speedup 1.0000x reference)
//
#include <hip/hip_runtime.h>
#include <hip/hip_bf16.h>

// Problem constants (B=2, T=4096, D=1024, H=512)
#define TT 4096
#define TD 1024
#define TM 8192            // B*T tokens
#define CN 3072            // big-GEMM N: [U 512 | Vn 512 | P 1024 | Y1 1024]
#define EPS 1e-5f

typedef __bf16 bf16;
typedef __bf16 bf16x2 __attribute__((ext_vector_type(2)));
typedef __bf16 bf16x4 __attribute__((ext_vector_type(4)));
typedef __bf16 bf16x8 __attribute__((ext_vector_type(8)));
typedef float  f32x4  __attribute__((ext_vector_type(4)));

#define GLOBAL_AS __attribute__((address_space(1)))
#define LDS_AS    __attribute__((address_space(3)))

// ---------------------------------------------------------------------------
// prep: one launch does all input marshalling.
//   blocks [0,4):        cvec[j] = sum_e wv_b[e] * merge_w[1024+e][j]   (f32)
//   blocks [4,8196):     cast x f32 -> Xbf bf16 [8192][1024]
//   then transposes (f32 -> bf16, 32x32 tiles):
//     w1_top^T   -> BigBT rows    0..511   (512 blocks)
//     w1_bot^T   -> BigBT rows  512..1023  (512 blocks)
//     merge_top^T-> BigBT rows 2048..3071  (1024 blocks)
//     merge_bot^T-> Amb [j][e]             (1024 blocks)
//   cast wv_w -> WvBf bf16 (1024 blocks)
// total grid = 12292
// ---------------------------------------------------------------------------
__global__ __launch_bounds__(256) void prep_kernel(const float* __restrict__ x,
                                                   const float* __restrict__ w1,
                                                   const float* __restrict__ wv_w,
                                                   const float* __restrict__ wv_b,
                                                   const float* __restrict__ merge_w,
                                                   bf16* __restrict__ Xbf,
                                                   bf16* __restrict__ BigBT,
                                                   bf16* __restrict__ Amb,
                                                   bf16* __restrict__ WvBf,
                                                   float* __restrict__ cvec) {
    __shared__ float tile[32][33];
    int b = blockIdx.x;
    const int tid = threadIdx.x;

    if (b < 4) {  // cvec (scheduled first so it overlaps the bulk work)
        int j = b * 256 + tid;
        const float* col = merge_w + (size_t)1024 * 1024 + j;
        float acc = 0.f;
#pragma unroll 16
        for (int e = 0; e < 1024; ++e) acc += wv_b[e] * col[(size_t)e * 1024];
        cvec[j] = acc;
        return;
    }
    b -= 4;
    if (b < 8192) {  // cast x
        int i = b * 256 + tid;
        float4 v = ((const float4*)x)[i];
        bf16x4 o; o[0] = (bf16)v.x; o[1] = (bf16)v.y; o[2] = (bf16)v.z; o[3] = (bf16)v.w;
        *(bf16x4*)(Xbf + (size_t)i * 4) = o;
        return;
    }
    b -= 8192;

    const float* src; bf16* dst; int srcN, tilesX, dstOff;
    if (b < 512)       {           src = w1;                        srcN = 512;  tilesX = 16; dst = BigBT; dstOff = 0;    }
    else if (b < 1024) { b -= 512; src = w1 + (size_t)1024 * 512;   srcN = 512;  tilesX = 16; dst = BigBT; dstOff = 512;  }
    else if (b < 2048) { b -= 1024; src = merge_w;                  srcN = 1024; tilesX = 32; dst = BigBT; dstOff = 2048; }
    else if (b < 3072) { b -= 2048; src = merge_w + (size_t)1024 * 1024; srcN = 1024; tilesX = 32; dst = Amb; dstOff = 0; }
    else {  // cast wv_w
        b -= 3072;
        int i = b * 256 + tid;
        float4 v = ((const float4*)wv_w)[i];
        bf16x4 o; o[0] = (bf16)v.x; o[1] = (bf16)v.y; o[2] = (bf16)v.z; o[3] = (bf16)v.w;
        *(bf16x4*)(WvBf + (size_t)i * 4) = o;
        return;
    }
    int n0 = (b % tilesX) * 32, k0 = (b / tilesX) * 32;
    int tx = tid & 31, ty = tid >> 5;
#pragma unroll
    for (int r = 0; r < 32; r += 8)
        tile[ty + r][tx] = src[(size_t)(k0 + ty + r) * srcN + n0 + tx];
    __syncthreads();
#pragma unroll
    for (int r = 0; r < 32; r += 8)
        dst[(size_t)(dstOff + n0 + ty + r) * 1024 + k0 + tx] = (bf16)tile[tx][ty + r];
}

// ---------------------------------------------------------------------------
// bf16 GEMM (B-transposed): C[M][N] = A[M][K] @ BT[N][K]^T, OutT out.
// 128x128 tile, BK=64, 4 waves, 64x64/wave, global_load_lds w=16,
// LDS chunk-XOR swizzle (verified conflict-free in r2: SQ_LDS_BANK_CONFLICT=0).
// SWIZ: remap so same-XCD blocks (linear%8) share a y-stripe -> A L2-resident.
// ---------------------------------------------------------------------------
template <typename OutT, bool SWIZ>
__global__ __launch_bounds__(256) void gemm_bt(const bf16* __restrict__ A, int lda,
                                               const bf16* __restrict__ BT,
                                               OutT* __restrict__ C, int N, int K) {
    __shared__ bf16 As[128 * 64];
    __shared__ bf16 Bs[128 * 64];
    int bx = blockIdx.x, by = blockIdx.y;
    if (SWIZ) {
        int L = by * gridDim.x + bx;
        int xcd = L & 7, idx = L >> 3;
        int nyx = gridDim.y >> 3;            // y-tiles per XCD (gridY % 8 == 0)
        by = xcd * nyx + idx / gridDim.x;
        bx = idx % gridDim.x;
    }
    const int m0 = by * 128;
    const int n0 = bx * 128;
    const int tid = threadIdx.x;
    const int wave = tid >> 6, lane = tid & 63;
    const int wr = (wave >> 1) * 64, wc = (wave & 1) * 64;
    const int lrow = lane & 15, cbase = lane >> 4;
    const int sw = lrow & 7;

    f32x4 acc[4][4] = {};

    for (int k0 = 0; k0 < K; k0 += 64) {
        __syncthreads();
#pragma unroll
        for (int c = 0; c < 4; ++c) {
            int e = (c * 256 + tid) * 8;   // bf16 elem offset in 128x64 tile
            int row = e >> 6;
            int q = (e >> 3) & 7;
            int gcol = ((q ^ (row & 7)) << 3);
            const bf16* ga = A  + (size_t)(m0 + row) * lda + k0 + gcol;
            const bf16* gb = BT + (size_t)(n0 + row) * K   + k0 + gcol;
            __builtin_amdgcn_global_load_lds((const GLOBAL_AS void*)ga,
                                             (LDS_AS void*)(As + e), 16, 0, 0);
            __builtin_amdgcn_global_load_lds((const GLOBAL_AS void*)gb,
                                             (LDS_AS void*)(Bs + e), 16, 0, 0);
        }
        __syncthreads();

#pragma unroll
        for (int kk = 0; kk < 2; ++kk) {
            const int qo = ((cbase + kk * 4) ^ sw) << 3;
            bf16x8 af[4], bfr[4];
#pragma unroll
            for (int i = 0; i < 4; ++i) {
                af[i]  = *(const bf16x8*)(As + (wr + i * 16 + lrow) * 64 + qo);
                bfr[i] = *(const bf16x8*)(Bs + (wc + i * 16 + lrow) * 64 + qo);
            }
#pragma unroll
            for (int i = 0; i < 4; ++i)
#pragma unroll
                for (int j = 0; j < 4; ++j)
                    acc[i][j] = __builtin_amdgcn_mfma_f32_16x16x32_bf16(af[i], bfr[j], acc[i][j], 0, 0, 0);
        }
    }

    // Epilogue: C/D layout col=lane&15, row=(lane>>4)*4+reg
    const int lr = (lane >> 4) * 4, lc = lane & 15;
#pragma unroll
    for (int i = 0; i < 4; ++i)
#pragma unroll
        for (int j = 0; j < 4; ++j)
#pragma unroll
            for (int r = 0; r < 4; ++r)
                C[(size_t)(m0 + wr + i * 16 + lr + r) * N + (n0 + wc + j * 16 + lc)]
                    = (OutT)acc[i][j][r];
}

// ---------------------------------------------------------------------------
// final: per token row — tau from U,Vn; y = Y1 + sum_w tau_w*P[t-w-1]
//        + tsum*cvec + merge_b; LayerNorm -> out.
// C layout per row (CN=3072): [U 0..511 | Vn 512..1023 | P 1024..2047 | Y1 2048..3071]
// ---------------------------------------------------------------------------
__global__ __launch_bounds__(256) void final_kernel(const bf16* __restrict__ C,
                                                    const float* __restrict__ b1,
                                                    const float* __restrict__ b2,
                                                    const float* __restrict__ w2,
                                                    const float* __restrict__ cvec,
                                                    const float* __restrict__ merge_b,
                                                    const float* __restrict__ gamma,
                                                    const float* __restrict__ beta,
                                                    float* __restrict__ out) {
    const int row = blockIdx.x;
    const int t = row & (TT - 1);
    const int tid = threadIdx.x;
    const bf16* Crow = C + (size_t)row * CN;

    // ---- tau phase: h = 2*tid, 2*tid+1
    const int h = tid * 2;
    bf16x2 u2 = *(const bf16x2*)(Crow + h);
    float2 b1v = *(const float2*)(b1 + h);
    float2 w2v = *(const float2*)(w2 + h);
    const float u0 = (float)u2[0] + b1v.x;
    const float u1 = (float)u2[1] + b1v.y;

    float partial[4];
#pragma unroll
    for (int w = 0; w < 4; ++w) {
        float vn0 = 0.f, vn1 = 0.f;
        if (t >= w + 1) {
            bf16x2 v2 = *(const bf16x2*)(C + (size_t)(row - w - 1) * CN + 512 + h);
            vn0 = (float)v2[0]; vn1 = (float)v2[1];
        }
        float z0 = u0 + vn0, z1 = u1 + vn1;
        float h0 = z0 / (1.f + __expf(-z0));
        float h1 = z1 / (1.f + __expf(-z1));
        partial[w] = h0 * w2v.x + h1 * w2v.y;
    }
#pragma unroll
    for (int w = 0; w < 4; ++w)
        for (int off = 32; off; off >>= 1)
            partial[w] += __shfl_down(partial[w], off, 64);

    __shared__ float red[4][4];
    __shared__ float staus[4];
    const int lane = tid & 63, wave = tid >> 6;
    if (lane == 0)
#pragma unroll
        for (int w = 0; w < 4; ++w) red[w][wave] = partial[w];
    __syncthreads();
    if (tid < 4) {
        float s = red[tid][0] + red[tid][1] + red[tid][2] + red[tid][3] + b2[0];
        staus[tid] = 1.f / (1.f + __expf(-s));
    }
    __syncthreads();
    const float tau0 = staus[0], tau1 = staus[1], tau2 = staus[2], tau3 = staus[3];
    const float tsum = tau0 + tau1 + tau2 + tau3;
    const float taus[4] = {tau0, tau1, tau2, tau3};

    // ---- output phase: d = 4*tid .. 4*tid+3
    const int d0 = tid * 4;
    bf16x4 y1 = *(const bf16x4*)(Crow + 2048 + d0);
    float4 cv = *(const float4*)(cvec + d0);
    float4 mb = *(const float4*)(merge_b + d0);
    float v[4] = {(float)y1[0] + tsum * cv.x + mb.x,
                  (float)y1[1] + tsum * cv.y + mb.y,
                  (float)y1[2] + tsum * cv.z + mb.z,
                  (float)y1[3] + tsum * cv.w + mb.w};
#pragma unroll
    for (int w = 0; w < 4; ++w) {
        if (t >= w + 1) {
            bf16x4 p = *(const bf16x4*)(C + (size_t)(row - w - 1) * CN + 1024 + d0);
#pragma unroll
            for (int j = 0; j < 4; ++j) v[j] += taus[w] * (float)p[j];
        }
    }

    // ---- LayerNorm
    float s = v[0] + v[1] + v[2] + v[3];
    float ss = v[0]*v[0] + v[1]*v[1] + v[2]*v[2] + v[3]*v[3];
    for (int off = 32; off; off >>= 1) {
        s  += __shfl_down(s, off, 64);
        ss += __shfl_down(ss, off, 64);
    }
    __shared__ float rs[4], rss[4];
    __shared__ float smu, srstd;
    if (lane == 0) { rs[wave] = s; rss[wave] = ss; }
    __syncthreads();
    if (tid == 0) {
        float S = rs[0] + rs[1] + rs[2] + rs[3];
        float SS = rss[0] + rss[1] + rss[2] + rss[3];
        float mu = S * (1.f / TD);
        float var = SS * (1.f / TD) - mu * mu;
        smu = mu; srstd = rsqrtf(var + EPS);
    }
    __syncthreads();
    const float mu = smu, r = srstd;
    float4 g  = *(const float4*)(gamma + d0);
    float4 bt = *(const float4*)(beta + d0);
    float4 o;
    o.x = (v[0] - mu) * r * g.x + bt.x;
    o.y = (v[1] - mu) * r * g.y + bt.y;
    o.z = (v[2] - mu) * r * g.z + bt.z;
    o.w = (v[3] - mu) * r * g.w + bt.w;
    *(float4*)(out + (size_t)row * TD + d0) = o;
}

// ---------------------------------------------------------------------------
extern "C" void kernel_launch(void* const* d_in, const int* in_sizes, int n_in,
                              void* d_out, int out_size, void* d_ws, size_t ws_size,
                              hipStream_t stream) {
    const float* x       = (const float*)d_in[0];
    const float* w1      = (const float*)d_in[1];
    const float* b1      = (const float*)d_in[2];
    const float* w2      = (const float*)d_in[3];
    const float* b2      = (const float*)d_in[4];
    const float* wv_w    = (const float*)d_in[5];
    const float* wv_b    = (const float*)d_in[6];
    const float* merge_w = (const float*)d_in[7];
    const float* merge_b = (const float*)d_in[8];
    const float* gamma   = (const float*)d_in[9];
    const float* beta    = (const float*)d_in[10];
    float* out = (float*)d_out;

    char* ws = (char*)d_ws;
    bf16*  Xbf   = (bf16*)ws;  ws += (size_t)TM * 1024 * 2;    // [8192][1024]
    bf16*  BigBT = (bf16*)ws;  ws += (size_t)CN * 1024 * 2;    // [3072 n][1024 k]
    bf16*  Amb   = (bf16*)ws;  ws += (size_t)1024 * 1024 * 2;  // merge_bot^T [j][e]
    bf16*  WvBf  = (bf16*)ws;  ws += (size_t)1024 * 1024 * 2;  // wv_w bf16 [d][e]
    float* cvec  = (float*)ws; ws += (size_t)1024 * 4;         // wv_b @ merge_bot
    bf16*  Cbuf  = (bf16*)ws;                                  // [8192][3072]

    // 1. marshal everything (one launch)
    prep_kernel<<<12292, 256, 0, stream>>>(x, w1, wv_w, wv_b, merge_w,
                                           Xbf, BigBT, Amb, WvBf, cvec);

    // 2. W'^T GEMM: BigBT[1024+j][d] = sum_e merge_bot[e][j] * wv_w[d][e]
    //    M=1024 (j), N=1024 (d), K=1024 (e)
    gemm_bt<bf16, false><<<dim3(8, 8), 256, 0, stream>>>(
        Amb, 1024, WvBf, BigBT + (size_t)1024 * 1024, 1024, 1024);

    // 3. big GEMM: Cbuf = Xbf @ BigBT^T   (M=8192, N=3072, K=1024)
    gemm_bt<bf16, true><<<dim3(CN / 128, TM / 128), 256, 0, stream>>>(
        Xbf, 1024, BigBT, Cbuf, CN, 1024);

    // 4. fused tau + combine + LayerNorm
    final_kernel<<<TM, 256, 0, stream>>>(Cbuf, b1, b2, w2, cvec, merge_b,
                                         gamma, beta, out);
}

// Round 4
// 202.227 us; speedup vs baseline: 1.1969x; 1.1969x over previous
//
#include <hip/hip_runtime.h>
#include <hip/hip_bf16.h>

// Problem constants (B=2, T=4096, D=1024, H=512)
#define TT 4096
#define TD 1024
#define TM 8192            // B*T tokens
#define CN 3072            // big-GEMM N: [U 512 | Vn 512 | P 1024 | Y1 1024]
#define EPS 1e-5f

typedef __bf16 bf16;
typedef __bf16 bf16x4 __attribute__((ext_vector_type(4)));
typedef __bf16 bf16x8 __attribute__((ext_vector_type(8)));
typedef float  f32x4  __attribute__((ext_vector_type(4)));

#define GLOBAL_AS __attribute__((address_space(1)))
#define LDS_AS    __attribute__((address_space(3)))

// ---------------------------------------------------------------------------
// prep: one launch does all input marshalling.
//  [0,16):        cvecP[ec][j] partials: sum over 256 e of wv_b[e]*merge_bot[e][j]
//  [16,8208):     cast x f32 -> Xbf bf16 [8192][1024]
//  transposes (f32 -> bf16, 32x32 tiles):
//    w1_top^T    -> BigBT rows    0..511   (512 blocks)
//    w1_bot^T    -> BigBT rows  512..1023  (512 blocks)
//    merge_top^T -> BigBT rows 2048..3071  (1024 blocks)
//    merge_bot^T -> Amb [j][e]             (1024 blocks)
//  cast wv_w -> WvBf bf16                  (1024 blocks)
// total grid = 12304
// ---------------------------------------------------------------------------
__global__ __launch_bounds__(256) void prep_kernel(const float* __restrict__ x,
                                                   const float* __restrict__ w1,
                                                   const float* __restrict__ wv_w,
                                                   const float* __restrict__ wv_b,
                                                   const float* __restrict__ merge_w,
                                                   bf16* __restrict__ Xbf,
                                                   bf16* __restrict__ BigBT,
                                                   bf16* __restrict__ Amb,
                                                   bf16* __restrict__ WvBf,
                                                   float* __restrict__ cvecP) {
    __shared__ float tile[32][33];
    int b = blockIdx.x;
    const int tid = threadIdx.x;

    if (b < 16) {  // cvec partials: jb = b&3 (256 j's), ec = b>>2 (256 e's)
        const int j = (b & 3) * 256 + tid;
        const int e0 = (b >> 2) * 256;
        const float* col = merge_w + (size_t)(1024 + e0) * 1024 + j;
        float acc = 0.f;
#pragma unroll 32
        for (int e = 0; e < 256; ++e) acc += wv_b[e0 + e] * col[(size_t)e * 1024];
        cvecP[(b >> 2) * 1024 + j] = acc;
        return;
    }
    b -= 16;
    if (b < 8192) {  // cast x
        int i = b * 256 + tid;
        float4 v = ((const float4*)x)[i];
        bf16x4 o; o[0] = (bf16)v.x; o[1] = (bf16)v.y; o[2] = (bf16)v.z; o[3] = (bf16)v.w;
        *(bf16x4*)(Xbf + (size_t)i * 4) = o;
        return;
    }
    b -= 8192;

    const float* src; bf16* dst; int srcN, tilesX, dstOff;
    if (b < 512)       {            src = w1;                        srcN = 512;  tilesX = 16; dst = BigBT; dstOff = 0;    }
    else if (b < 1024) { b -= 512;  src = w1 + (size_t)1024 * 512;   srcN = 512;  tilesX = 16; dst = BigBT; dstOff = 512;  }
    else if (b < 2048) { b -= 1024; src = merge_w;                   srcN = 1024; tilesX = 32; dst = BigBT; dstOff = 2048; }
    else if (b < 3072) { b -= 2048; src = merge_w + (size_t)1024 * 1024; srcN = 1024; tilesX = 32; dst = Amb; dstOff = 0; }
    else {  // cast wv_w
        b -= 3072;
        int i = b * 256 + tid;
        float4 v = ((const float4*)wv_w)[i];
        bf16x4 o; o[0] = (bf16)v.x; o[1] = (bf16)v.y; o[2] = (bf16)v.z; o[3] = (bf16)v.w;
        *(bf16x4*)(WvBf + (size_t)i * 4) = o;
        return;
    }
    int n0 = (b % tilesX) * 32, k0 = (b / tilesX) * 32;
    int tx = tid & 31, ty = tid >> 5;
#pragma unroll
    for (int r = 0; r < 32; r += 8)
        tile[ty + r][tx] = src[(size_t)(k0 + ty + r) * srcN + n0 + tx];
    __syncthreads();
#pragma unroll
    for (int r = 0; r < 32; r += 8)
        dst[(size_t)(dstOff + n0 + ty + r) * 1024 + k0 + tx] = (bf16)tile[tx][ty + r];
}

// ---------------------------------------------------------------------------
// wprime: W'^T GEMM on 64x64 tiles (grid 257, full-GPU: 256 blocks, K=16 iters)
//   C[j][d] = sum_e Amb[j][e] * WvBf[d][e]   (M=N=K=1024) -> BigBT rows 1024..2047
//   block 256: reduce cvecP[4][1024] -> cvec[1024]
// ---------------------------------------------------------------------------
__global__ __launch_bounds__(256) void wprime_kernel(const bf16* __restrict__ Amb,
                                                     const bf16* __restrict__ WvBf,
                                                     bf16* __restrict__ Wout,
                                                     const float* __restrict__ cvecP,
                                                     float* __restrict__ cvec) {
    int b = blockIdx.x;
    if (b == 256) {
        int j = threadIdx.x * 4;
        float4 s0 = *(const float4*)(cvecP + j);
        float4 s1 = *(const float4*)(cvecP + 1024 + j);
        float4 s2 = *(const float4*)(cvecP + 2048 + j);
        float4 s3 = *(const float4*)(cvecP + 3072 + j);
        float4 o = {s0.x + s1.x + s2.x + s3.x, s0.y + s1.y + s2.y + s3.y,
                    s0.z + s1.z + s2.z + s3.z, s0.w + s1.w + s2.w + s3.w};
        *(float4*)(cvec + j) = o;
        return;
    }
    __shared__ bf16 As[64 * 64];
    __shared__ bf16 Bs[64 * 64];
    const int m0 = (b >> 4) * 64;
    const int n0 = (b & 15) * 64;
    const int tid = threadIdx.x;
    const int wave = tid >> 6, lane = tid & 63;
    const int wr = (wave >> 1) * 32, wc = (wave & 1) * 32;
    const int lrow = lane & 15, cbase = lane >> 4;
    const int sw = lrow & 7;

    f32x4 acc[2][2] = {};

    for (int k0 = 0; k0 < 1024; k0 += 64) {
        __syncthreads();
#pragma unroll
        for (int c = 0; c < 2; ++c) {
            int e = (c * 256 + tid) * 8;   // elem offset in 64x64 tile
            int row = e >> 6;
            int q = (e >> 3) & 7;
            int gcol = ((q ^ (row & 7)) << 3);
            const bf16* ga = Amb  + (size_t)(m0 + row) * 1024 + k0 + gcol;
            const bf16* gb = WvBf + (size_t)(n0 + row) * 1024 + k0 + gcol;
            __builtin_amdgcn_global_load_lds((const GLOBAL_AS void*)ga,
                                             (LDS_AS void*)(As + e), 16, 0, 0);
            __builtin_amdgcn_global_load_lds((const GLOBAL_AS void*)gb,
                                             (LDS_AS void*)(Bs + e), 16, 0, 0);
        }
        __syncthreads();

#pragma unroll
        for (int kk = 0; kk < 2; ++kk) {
            const int qo = ((cbase + kk * 4) ^ sw) << 3;
            bf16x8 af[2], bfr[2];
#pragma unroll
            for (int i = 0; i < 2; ++i) {
                af[i]  = *(const bf16x8*)(As + (wr + i * 16 + lrow) * 64 + qo);
                bfr[i] = *(const bf16x8*)(Bs + (wc + i * 16 + lrow) * 64 + qo);
            }
#pragma unroll
            for (int i = 0; i < 2; ++i)
#pragma unroll
                for (int j = 0; j < 2; ++j)
                    acc[i][j] = __builtin_amdgcn_mfma_f32_16x16x32_bf16(af[i], bfr[j], acc[i][j], 0, 0, 0);
        }
    }

    const int lr = (lane >> 4) * 4, lc = lane & 15;
#pragma unroll
    for (int i = 0; i < 2; ++i)
#pragma unroll
        for (int j = 0; j < 2; ++j)
#pragma unroll
            for (int r = 0; r < 4; ++r)
                Wout[(size_t)(m0 + wr + i * 16 + lr + r) * 1024 + (n0 + wc + j * 16 + lc)]
                    = (bf16)acc[i][j][r];
}

// ---------------------------------------------------------------------------
// bf16 GEMM (B-transposed): C[M][N] = A[M][K] @ BT[N][K]^T, bf16 out.
// 128x128 tile, BK=64, 4 waves, 64x64/wave, global_load_lds w=16,
// LDS chunk-XOR swizzle (verified conflict-free: SQ_LDS_BANK_CONFLICT=0).
// SWIZ: same-XCD blocks (linear%8) share a y-stripe -> A L2-resident (verified r3).
// ---------------------------------------------------------------------------
template <bool SWIZ>
__global__ __launch_bounds__(256) void gemm_bt(const bf16* __restrict__ A, int lda,
                                               const bf16* __restrict__ BT,
                                               bf16* __restrict__ C, int N, int K) {
    __shared__ bf16 As[128 * 64];
    __shared__ bf16 Bs[128 * 64];
    int bx = blockIdx.x, by = blockIdx.y;
    if (SWIZ) {
        int L = by * gridDim.x + bx;
        int xcd = L & 7, idx = L >> 3;
        int nyx = gridDim.y >> 3;            // y-tiles per XCD (gridY % 8 == 0)
        by = xcd * nyx + idx / gridDim.x;
        bx = idx % gridDim.x;
    }
    const int m0 = by * 128;
    const int n0 = bx * 128;
    const int tid = threadIdx.x;
    const int wave = tid >> 6, lane = tid & 63;
    const int wr = (wave >> 1) * 64, wc = (wave & 1) * 64;
    const int lrow = lane & 15, cbase = lane >> 4;
    const int sw = lrow & 7;

    f32x4 acc[4][4] = {};

    for (int k0 = 0; k0 < K; k0 += 64) {
        __syncthreads();
#pragma unroll
        for (int c = 0; c < 4; ++c) {
            int e = (c * 256 + tid) * 8;   // bf16 elem offset in 128x64 tile
            int row = e >> 6;
            int q = (e >> 3) & 7;
            int gcol = ((q ^ (row & 7)) << 3);
            const bf16* ga = A  + (size_t)(m0 + row) * lda + k0 + gcol;
            const bf16* gb = BT + (size_t)(n0 + row) * K   + k0 + gcol;
            __builtin_amdgcn_global_load_lds((const GLOBAL_AS void*)ga,
                                             (LDS_AS void*)(As + e), 16, 0, 0);
            __builtin_amdgcn_global_load_lds((const GLOBAL_AS void*)gb,
                                             (LDS_AS void*)(Bs + e), 16, 0, 0);
        }
        __syncthreads();

#pragma unroll
        for (int kk = 0; kk < 2; ++kk) {
            const int qo = ((cbase + kk * 4) ^ sw) << 3;
            bf16x8 af[4], bfr[4];
#pragma unroll
            for (int i = 0; i < 4; ++i) {
                af[i]  = *(const bf16x8*)(As + (wr + i * 16 + lrow) * 64 + qo);
                bfr[i] = *(const bf16x8*)(Bs + (wc + i * 16 + lrow) * 64 + qo);
            }
#pragma unroll
            for (int i = 0; i < 4; ++i)
#pragma unroll
                for (int j = 0; j < 4; ++j)
                    acc[i][j] = __builtin_amdgcn_mfma_f32_16x16x32_bf16(af[i], bfr[j], acc[i][j], 0, 0, 0);
        }
    }

    const int lr = (lane >> 4) * 4, lc = lane & 15;
#pragma unroll
    for (int i = 0; i < 4; ++i)
#pragma unroll
        for (int j = 0; j < 4; ++j)
#pragma unroll
            for (int r = 0; r < 4; ++r)
                C[(size_t)(m0 + wr + i * 16 + lr + r) * N + (n0 + wc + j * 16 + lc)]
                    = (bf16)acc[i][j][r];
}

// ---------------------------------------------------------------------------
// final: wave-per-token, 4 tokens/block, zero __syncthreads.
// Per row (CN=3072): [U 0..511 | Vn 512..1023 | P 1024..2047 | Y1 2048..3071]
// tau_w = sigmoid(b2 + sum_h w2[h]*silu(U[h]+b1[h]+Vn[t-w-1][h]))
// y = Y1 + sum_w tau_w*P[t-w-1] + tsum*cvec + merge_b; LayerNorm -> out.
// ---------------------------------------------------------------------------
__global__ __launch_bounds__(256) void final_kernel(const bf16* __restrict__ C,
                                                    const float* __restrict__ b1,
                                                    const float* __restrict__ b2,
                                                    const float* __restrict__ w2,
                                                    const float* __restrict__ cvec,
                                                    const float* __restrict__ merge_b,
                                                    const float* __restrict__ gamma,
                                                    const float* __restrict__ beta,
                                                    float* __restrict__ out) {
    const int wave = threadIdx.x >> 6, lane = threadIdx.x & 63;
    const int row = blockIdx.x * 4 + wave;
    const int t = row & (TT - 1);
    const bf16* Crow = C + (size_t)row * CN;

    // ---- tau phase: lane owns h = lane*8 .. +7
    const int h0 = lane * 8;
    bf16x8 u8 = *(const bf16x8*)(Crow + h0);
    float4 b1a = *(const float4*)(b1 + h0), b1b = *(const float4*)(b1 + h0 + 4);
    float4 w2a = *(const float4*)(w2 + h0), w2b = *(const float4*)(w2 + h0 + 4);
    float u[8] = {(float)u8[0] + b1a.x, (float)u8[1] + b1a.y,
                  (float)u8[2] + b1a.z, (float)u8[3] + b1a.w,
                  (float)u8[4] + b1b.x, (float)u8[5] + b1b.y,
                  (float)u8[6] + b1b.z, (float)u8[7] + b1b.w};
    const float w2v[8] = {w2a.x, w2a.y, w2a.z, w2a.w, w2b.x, w2b.y, w2b.z, w2b.w};

    float partial[4];
#pragma unroll
    for (int w = 0; w < 4; ++w) {
        float p = 0.f;
        if (t >= w + 1) {
            bf16x8 v8 = *(const bf16x8*)(C + (size_t)(row - w - 1) * CN + 512 + h0);
#pragma unroll
            for (int k = 0; k < 8; ++k) {
                float z = u[k] + (float)v8[k];
                p += (z / (1.f + __expf(-z))) * w2v[k];
            }
        } else {
#pragma unroll
            for (int k = 0; k < 8; ++k) {
                float z = u[k];
                p += (z / (1.f + __expf(-z))) * w2v[k];
            }
        }
        partial[w] = p;
    }
    // butterfly reduce -> all lanes hold the sum
#pragma unroll
    for (int w = 0; w < 4; ++w)
#pragma unroll
        for (int off = 1; off < 64; off <<= 1)
            partial[w] += __shfl_xor(partial[w], off, 64);

    const float bias2 = b2[0];
    float taus[4];
#pragma unroll
    for (int w = 0; w < 4; ++w)
        taus[w] = 1.f / (1.f + __expf(-(partial[w] + bias2)));
    const float tsum = taus[0] + taus[1] + taus[2] + taus[3];

    // ---- output phase: lane owns d = lane*16 .. +15
    const int d0 = lane * 16;
    bf16x8 y1a = *(const bf16x8*)(Crow + 2048 + d0);
    bf16x8 y1b = *(const bf16x8*)(Crow + 2048 + d0 + 8);
    float v[16];
#pragma unroll
    for (int k = 0; k < 8; ++k) { v[k] = (float)y1a[k]; v[8 + k] = (float)y1b[k]; }
#pragma unroll
    for (int q = 0; q < 4; ++q) {
        float4 cv = *(const float4*)(cvec + d0 + q * 4);
        float4 mb = *(const float4*)(merge_b + d0 + q * 4);
        v[q*4+0] += tsum * cv.x + mb.x; v[q*4+1] += tsum * cv.y + mb.y;
        v[q*4+2] += tsum * cv.z + mb.z; v[q*4+3] += tsum * cv.w + mb.w;
    }
#pragma unroll
    for (int w = 0; w < 4; ++w) {
        if (t >= w + 1) {
            const bf16* Pn = C + (size_t)(row - w - 1) * CN + 1024 + d0;
            bf16x8 pa = *(const bf16x8*)Pn;
            bf16x8 pb = *(const bf16x8*)(Pn + 8);
#pragma unroll
            for (int k = 0; k < 8; ++k) {
                v[k] += taus[w] * (float)pa[k];
                v[8 + k] += taus[w] * (float)pb[k];
            }
        }
    }

    // ---- LayerNorm (whole row lives in this wave)
    float s = 0.f, ss = 0.f;
#pragma unroll
    for (int k = 0; k < 16; ++k) { s += v[k]; ss += v[k] * v[k]; }
#pragma unroll
    for (int off = 1; off < 64; off <<= 1) {
        s  += __shfl_xor(s, off, 64);
        ss += __shfl_xor(ss, off, 64);
    }
    const float mu = s * (1.f / TD);
    const float var = ss * (1.f / TD) - mu * mu;
    const float r = rsqrtf(var + EPS);

#pragma unroll
    for (int q = 0; q < 4; ++q) {
        float4 g  = *(const float4*)(gamma + d0 + q * 4);
        float4 bt = *(const float4*)(beta + d0 + q * 4);
        float4 o;
        o.x = (v[q*4+0] - mu) * r * g.x + bt.x;
        o.y = (v[q*4+1] - mu) * r * g.y + bt.y;
        o.z = (v[q*4+2] - mu) * r * g.z + bt.z;
        o.w = (v[q*4+3] - mu) * r * g.w + bt.w;
        *(float4*)(out + (size_t)row * TD + d0 + q * 4) = o;
    }
}

// ---------------------------------------------------------------------------
extern "C" void kernel_launch(void* const* d_in, const int* in_sizes, int n_in,
                              void* d_out, int out_size, void* d_ws, size_t ws_size,
                              hipStream_t stream) {
    const float* x       = (const float*)d_in[0];
    const float* w1      = (const float*)d_in[1];
    const float* b1      = (const float*)d_in[2];
    const float* w2      = (const float*)d_in[3];
    const float* b2      = (const float*)d_in[4];
    const float* wv_w    = (const float*)d_in[5];
    const float* wv_b    = (const float*)d_in[6];
    const float* merge_w = (const float*)d_in[7];
    const float* merge_b = (const float*)d_in[8];
    const float* gamma   = (const float*)d_in[9];
    const float* beta    = (const float*)d_in[10];
    float* out = (float*)d_out;

    char* ws = (char*)d_ws;
    bf16*  Xbf   = (bf16*)ws;  ws += (size_t)TM * 1024 * 2;    // [8192][1024]
    bf16*  BigBT = (bf16*)ws;  ws += (size_t)CN * 1024 * 2;    // [3072 n][1024 k]
    bf16*  Amb   = (bf16*)ws;  ws += (size_t)1024 * 1024 * 2;  // merge_bot^T [j][e]
    bf16*  WvBf  = (bf16*)ws;  ws += (size_t)1024 * 1024 * 2;  // wv_w bf16 [d][e]
    float* cvecP = (float*)ws; ws += (size_t)4 * 1024 * 4;     // partials
    float* cvec  = (float*)ws; ws += (size_t)1024 * 4;         // wv_b @ merge_bot
    bf16*  Cbuf  = (bf16*)ws;                                  // [8192][3072]

    // 1. marshal everything (one launch)
    prep_kernel<<<12304, 256, 0, stream>>>(x, w1, wv_w, wv_b, merge_w,
                                           Xbf, BigBT, Amb, WvBf, cvecP);

    // 2. W' GEMM (full-GPU 64x64 tiles) + cvec reduction
    wprime_kernel<<<257, 256, 0, stream>>>(Amb, WvBf, BigBT + (size_t)1024 * 1024,
                                           cvecP, cvec);

    // 3. big GEMM: Cbuf = Xbf @ BigBT^T   (M=8192, N=3072, K=1024)
    gemm_bt<true><<<dim3(CN / 128, TM / 128), 256, 0, stream>>>(
        Xbf, 1024, BigBT, Cbuf, CN, 1024);

    // 4. fused tau + combine + LayerNorm (wave-per-token, no barriers)
    final_kernel<<<TM / 4, 256, 0, stream>>>(Cbuf, b1, b2, w2, cvec, merge_b,
                                             gamma, beta, out);
}

// Round 5
// 195.123 us; speedup vs baseline: 1.2405x; 1.0364x over previous
//
#include <hip/hip_runtime.h>
#include <hip/hip_bf16.h>

// Problem constants (B=2, T=4096, D=1024, H=512)
#define TT 4096
#define TD 1024
#define TM 8192            // B*T tokens
#define CN 3072            // big-GEMM N: [U 512 | Vn 512 | P 1024 | Y1 1024]
#define EPS 1e-5f

typedef __bf16 bf16;
typedef __bf16 bf16x4 __attribute__((ext_vector_type(4)));
typedef __bf16 bf16x8 __attribute__((ext_vector_type(8)));
typedef float  f32x4  __attribute__((ext_vector_type(4)));

#define GLOBAL_AS __attribute__((address_space(1)))
#define LDS_AS    __attribute__((address_space(3)))

// ---------------------------------------------------------------------------
// prep: one launch does all input marshalling (unchanged from r4).
// ---------------------------------------------------------------------------
__global__ __launch_bounds__(256) void prep_kernel(const float* __restrict__ x,
                                                   const float* __restrict__ w1,
                                                   const float* __restrict__ wv_w,
                                                   const float* __restrict__ wv_b,
                                                   const float* __restrict__ merge_w,
                                                   bf16* __restrict__ Xbf,
                                                   bf16* __restrict__ BigBT,
                                                   bf16* __restrict__ Amb,
                                                   bf16* __restrict__ WvBf,
                                                   float* __restrict__ cvecP) {
    __shared__ float tile[32][33];
    int b = blockIdx.x;
    const int tid = threadIdx.x;

    if (b < 16) {  // cvec partials: jb = b&3 (256 j's), ec = b>>2 (256 e's)
        const int j = (b & 3) * 256 + tid;
        const int e0 = (b >> 2) * 256;
        const float* col = merge_w + (size_t)(1024 + e0) * 1024 + j;
        float acc = 0.f;
#pragma unroll 32
        for (int e = 0; e < 256; ++e) acc += wv_b[e0 + e] * col[(size_t)e * 1024];
        cvecP[(b >> 2) * 1024 + j] = acc;
        return;
    }
    b -= 16;
    if (b < 8192) {  // cast x
        int i = b * 256 + tid;
        float4 v = ((const float4*)x)[i];
        bf16x4 o; o[0] = (bf16)v.x; o[1] = (bf16)v.y; o[2] = (bf16)v.z; o[3] = (bf16)v.w;
        *(bf16x4*)(Xbf + (size_t)i * 4) = o;
        return;
    }
    b -= 8192;

    const float* src; bf16* dst; int srcN, tilesX, dstOff;
    if (b < 512)       {            src = w1;                        srcN = 512;  tilesX = 16; dst = BigBT; dstOff = 0;    }
    else if (b < 1024) { b -= 512;  src = w1 + (size_t)1024 * 512;   srcN = 512;  tilesX = 16; dst = BigBT; dstOff = 512;  }
    else if (b < 2048) { b -= 1024; src = merge_w;                   srcN = 1024; tilesX = 32; dst = BigBT; dstOff = 2048; }
    else if (b < 3072) { b -= 2048; src = merge_w + (size_t)1024 * 1024; srcN = 1024; tilesX = 32; dst = Amb; dstOff = 0; }
    else {  // cast wv_w
        b -= 3072;
        int i = b * 256 + tid;
        float4 v = ((const float4*)wv_w)[i];
        bf16x4 o; o[0] = (bf16)v.x; o[1] = (bf16)v.y; o[2] = (bf16)v.z; o[3] = (bf16)v.w;
        *(bf16x4*)(WvBf + (size_t)i * 4) = o;
        return;
    }
    int n0 = (b % tilesX) * 32, k0 = (b / tilesX) * 32;
    int tx = tid & 31, ty = tid >> 5;
#pragma unroll
    for (int r = 0; r < 32; r += 8)
        tile[ty + r][tx] = src[(size_t)(k0 + ty + r) * srcN + n0 + tx];
    __syncthreads();
#pragma unroll
    for (int r = 0; r < 32; r += 8)
        dst[(size_t)(dstOff + n0 + ty + r) * 1024 + k0 + tx] = (bf16)tile[tx][ty + r];
}

// ---------------------------------------------------------------------------
// wprime: W' GEMM on 64x64 tiles (grid 257) + cvec reduction (unchanged from r4)
// ---------------------------------------------------------------------------
__global__ __launch_bounds__(256) void wprime_kernel(const bf16* __restrict__ Amb,
                                                     const bf16* __restrict__ WvBf,
                                                     bf16* __restrict__ Wout,
                                                     const float* __restrict__ cvecP,
                                                     float* __restrict__ cvec) {
    int b = blockIdx.x;
    if (b == 256) {
        int j = threadIdx.x * 4;
        float4 s0 = *(const float4*)(cvecP + j);
        float4 s1 = *(const float4*)(cvecP + 1024 + j);
        float4 s2 = *(const float4*)(cvecP + 2048 + j);
        float4 s3 = *(const float4*)(cvecP + 3072 + j);
        float4 o = {s0.x + s1.x + s2.x + s3.x, s0.y + s1.y + s2.y + s3.y,
                    s0.z + s1.z + s2.z + s3.z, s0.w + s1.w + s2.w + s3.w};
        *(float4*)(cvec + j) = o;
        return;
    }
    __shared__ bf16 As[64 * 64];
    __shared__ bf16 Bs[64 * 64];
    const int m0 = (b >> 4) * 64;
    const int n0 = (b & 15) * 64;
    const int tid = threadIdx.x;
    const int wave = tid >> 6, lane = tid & 63;
    const int wr = (wave >> 1) * 32, wc = (wave & 1) * 32;
    const int lrow = lane & 15, cbase = lane >> 4;
    const int sw = lrow & 7;

    f32x4 acc[2][2] = {};

    for (int k0 = 0; k0 < 1024; k0 += 64) {
        __syncthreads();
#pragma unroll
        for (int c = 0; c < 2; ++c) {
            int e = (c * 256 + tid) * 8;
            int row = e >> 6;
            int q = (e >> 3) & 7;
            int gcol = ((q ^ (row & 7)) << 3);
            const bf16* ga = Amb  + (size_t)(m0 + row) * 1024 + k0 + gcol;
            const bf16* gb = WvBf + (size_t)(n0 + row) * 1024 + k0 + gcol;
            __builtin_amdgcn_global_load_lds((const GLOBAL_AS void*)ga,
                                             (LDS_AS void*)(As + e), 16, 0, 0);
            __builtin_amdgcn_global_load_lds((const GLOBAL_AS void*)gb,
                                             (LDS_AS void*)(Bs + e), 16, 0, 0);
        }
        __syncthreads();

#pragma unroll
        for (int kk = 0; kk < 2; ++kk) {
            const int qo = ((cbase + kk * 4) ^ sw) << 3;
            bf16x8 af[2], bfr[2];
#pragma unroll
            for (int i = 0; i < 2; ++i) {
                af[i]  = *(const bf16x8*)(As + (wr + i * 16 + lrow) * 64 + qo);
                bfr[i] = *(const bf16x8*)(Bs + (wc + i * 16 + lrow) * 64 + qo);
            }
#pragma unroll
            for (int i = 0; i < 2; ++i)
#pragma unroll
                for (int j = 0; j < 2; ++j)
                    acc[i][j] = __builtin_amdgcn_mfma_f32_16x16x32_bf16(af[i], bfr[j], acc[i][j], 0, 0, 0);
        }
    }

    const int lr = (lane >> 4) * 4, lc = lane & 15;
#pragma unroll
    for (int i = 0; i < 2; ++i)
#pragma unroll
        for (int j = 0; j < 2; ++j)
#pragma unroll
            for (int r = 0; r < 4; ++r)
                Wout[(size_t)(m0 + wr + i * 16 + lr + r) * 1024 + (n0 + wc + j * 16 + lc)]
                    = (bf16)acc[i][j][r];
}

// ---------------------------------------------------------------------------
// Big GEMM: C[M][N] = A[M][K] @ BT[N][K]^T, bf16 out.
// 256Mx96N block tile, wave = 64x96 (acc[4][6]) -> 39.3 FLOP/LDS-byte vs 32.8
// at 64x64 (the r4 kernel was LDS-read-bound). BK=64, XOR chunk swizzle
// (verified conflict-free), global_load_lds w=16.
// Grid 32x32 = 1024 blocks = exactly 2 residency waves at 2 blocks/CU
// (SMEM sized 57344B + launch_bounds(256,2) pin 2 blocks/CU).
// Epilogue: wave-local LDS repack (stride-104 rows) -> dwordx4 C stores.
// XCD swizzle: same-XCD blocks share a 256-row y-stripe (A L2-resident).
// ---------------------------------------------------------------------------
__global__ __launch_bounds__(256, 2) void gemm_big(const bf16* __restrict__ A,
                                                   const bf16* __restrict__ BT,
                                                   bf16* __restrict__ C) {
    __shared__ bf16 SMEM[28672];          // 57344 B: staging 45056 B / epi 53248 B
    bf16* As = SMEM;                      // 256x64
    bf16* Bs = SMEM + 16384;              // 96x64
    const int NB = 3072, K = 1024;

    int bx = blockIdx.x, by = blockIdx.y; // 32 x 32
    {   // XCD swizzle
        int L = by * 32 + bx;
        int xcd = L & 7, idx = L >> 3;    // idx in 0..127
        by = xcd * 4 + (idx >> 5);
        bx = idx & 31;
    }
    const int m0 = by * 256;
    const int n0 = bx * 96;
    const int tid = threadIdx.x;
    const int wave = tid >> 6, lane = tid & 63;
    const int wr = wave * 64;             // wave's M offset in tile
    const int lrow = lane & 15, cbase = lane >> 4;
    const int sw = lrow & 7;

    f32x4 acc[4][6] = {};

    for (int k0 = 0; k0 < K; k0 += 64) {
        __syncthreads();
#pragma unroll
        for (int c = 0; c < 11; ++c) {    // 8 A-chunks + 3 B-chunks
            if (c < 8) {
                int e = (c * 256 + tid) * 8;        // in 256x64 A tile
                int row = e >> 6;
                int q = (e >> 3) & 7;
                int gcol = ((q ^ (row & 7)) << 3);
                const bf16* ga = A + (size_t)(m0 + row) * K + k0 + gcol;
                __builtin_amdgcn_global_load_lds((const GLOBAL_AS void*)ga,
                                                 (LDS_AS void*)(As + e), 16, 0, 0);
            } else {
                int e = ((c - 8) * 256 + tid) * 8;  // in 96x64 B tile
                int row = e >> 6;
                int q = (e >> 3) & 7;
                int gcol = ((q ^ (row & 7)) << 3);
                const bf16* gb = BT + (size_t)(n0 + row) * K + k0 + gcol;
                __builtin_amdgcn_global_load_lds((const GLOBAL_AS void*)gb,
                                                 (LDS_AS void*)(Bs + e), 16, 0, 0);
            }
        }
        __syncthreads();

#pragma unroll
        for (int kk = 0; kk < 2; ++kk) {
            const int qo = ((cbase + kk * 4) ^ sw) << 3;
            bf16x8 af[4], bfr[6];
#pragma unroll
            for (int i = 0; i < 4; ++i)
                af[i] = *(const bf16x8*)(As + (wr + i * 16 + lrow) * 64 + qo);
#pragma unroll
            for (int j = 0; j < 6; ++j)
                bfr[j] = *(const bf16x8*)(Bs + (j * 16 + lrow) * 64 + qo);
#pragma unroll
            for (int i = 0; i < 4; ++i)
#pragma unroll
                for (int j = 0; j < 6; ++j)
                    acc[i][j] = __builtin_amdgcn_mfma_f32_16x16x32_bf16(af[i], bfr[j], acc[i][j], 0, 0, 0);
        }
    }

    // ---- Epilogue: repack via LDS (wave-local region, stride 104 bf16) ----
    __syncthreads();                       // all waves done reading staging LDS
    bf16* ep = SMEM + wave * 6656;         // 64 rows x 104 stride
    const int lr = (lane >> 4) * 4, lc = lane & 15;
#pragma unroll
    for (int i = 0; i < 4; ++i)
#pragma unroll
        for (int j = 0; j < 6; ++j)
#pragma unroll
            for (int r = 0; r < 4; ++r)
                ep[(i * 16 + lr + r) * 104 + (j * 16 + lc)] = (bf16)acc[i][j][r];
    __syncthreads();                       // (wave-local would suffice; safe)

    bf16* Cw = C + (size_t)(m0 + wr) * NB + n0;
    // cols 0..63: 8 insts, 8 rows x 8 lanes x 16B
#pragma unroll
    for (int p = 0; p < 8; ++p) {
        int R = p * 8 + (lane >> 3);
        int Ccol = (lane & 7) * 8;
        bf16x8 v = *(const bf16x8*)(ep + R * 104 + Ccol);
        *(bf16x8*)(Cw + (size_t)R * NB + Ccol) = v;
    }
    // cols 64..95: 4 insts, 16 rows x 4 lanes x 16B
#pragma unroll
    for (int p = 0; p < 4; ++p) {
        int R = p * 16 + (lane >> 2);
        int Ccol = 64 + (lane & 3) * 8;
        bf16x8 v = *(const bf16x8*)(ep + R * 104 + Ccol);
        *(bf16x8*)(Cw + (size_t)R * NB + Ccol) = v;
    }
}

// ---------------------------------------------------------------------------
// final: wave-per-token, 4 tokens/block, zero __syncthreads (unchanged from r4).
// ---------------------------------------------------------------------------
__global__ __launch_bounds__(256) void final_kernel(const bf16* __restrict__ C,
                                                    const float* __restrict__ b1,
                                                    const float* __restrict__ b2,
                                                    const float* __restrict__ w2,
                                                    const float* __restrict__ cvec,
                                                    const float* __restrict__ merge_b,
                                                    const float* __restrict__ gamma,
                                                    const float* __restrict__ beta,
                                                    float* __restrict__ out) {
    const int wave = threadIdx.x >> 6, lane = threadIdx.x & 63;
    const int row = blockIdx.x * 4 + wave;
    const int t = row & (TT - 1);
    const bf16* Crow = C + (size_t)row * CN;

    const int h0 = lane * 8;
    bf16x8 u8 = *(const bf16x8*)(Crow + h0);
    float4 b1a = *(const float4*)(b1 + h0), b1b = *(const float4*)(b1 + h0 + 4);
    float4 w2a = *(const float4*)(w2 + h0), w2b = *(const float4*)(w2 + h0 + 4);
    float u[8] = {(float)u8[0] + b1a.x, (float)u8[1] + b1a.y,
                  (float)u8[2] + b1a.z, (float)u8[3] + b1a.w,
                  (float)u8[4] + b1b.x, (float)u8[5] + b1b.y,
                  (float)u8[6] + b1b.z, (float)u8[7] + b1b.w};
    const float w2v[8] = {w2a.x, w2a.y, w2a.z, w2a.w, w2b.x, w2b.y, w2b.z, w2b.w};

    float partial[4];
#pragma unroll
    for (int w = 0; w < 4; ++w) {
        float p = 0.f;
        if (t >= w + 1) {
            bf16x8 v8 = *(const bf16x8*)(C + (size_t)(row - w - 1) * CN + 512 + h0);
#pragma unroll
            for (int k = 0; k < 8; ++k) {
                float z = u[k] + (float)v8[k];
                p += (z / (1.f + __expf(-z))) * w2v[k];
            }
        } else {
#pragma unroll
            for (int k = 0; k < 8; ++k) {
                float z = u[k];
                p += (z / (1.f + __expf(-z))) * w2v[k];
            }
        }
        partial[w] = p;
    }
#pragma unroll
    for (int w = 0; w < 4; ++w)
#pragma unroll
        for (int off = 1; off < 64; off <<= 1)
            partial[w] += __shfl_xor(partial[w], off, 64);

    const float bias2 = b2[0];
    float taus[4];
#pragma unroll
    for (int w = 0; w < 4; ++w)
        taus[w] = 1.f / (1.f + __expf(-(partial[w] + bias2)));
    const float tsum = taus[0] + taus[1] + taus[2] + taus[3];

    const int d0 = lane * 16;
    bf16x8 y1a = *(const bf16x8*)(Crow + 2048 + d0);
    bf16x8 y1b = *(const bf16x8*)(Crow + 2048 + d0 + 8);
    float v[16];
#pragma unroll
    for (int k = 0; k < 8; ++k) { v[k] = (float)y1a[k]; v[8 + k] = (float)y1b[k]; }
#pragma unroll
    for (int q = 0; q < 4; ++q) {
        float4 cv = *(const float4*)(cvec + d0 + q * 4);
        float4 mb = *(const float4*)(merge_b + d0 + q * 4);
        v[q*4+0] += tsum * cv.x + mb.x; v[q*4+1] += tsum * cv.y + mb.y;
        v[q*4+2] += tsum * cv.z + mb.z; v[q*4+3] += tsum * cv.w + mb.w;
    }
#pragma unroll
    for (int w = 0; w < 4; ++w) {
        if (t >= w + 1) {
            const bf16* Pn = C + (size_t)(row - w - 1) * CN + 1024 + d0;
            bf16x8 pa = *(const bf16x8*)Pn;
            bf16x8 pb = *(const bf16x8*)(Pn + 8);
#pragma unroll
            for (int k = 0; k < 8; ++k) {
                v[k] += taus[w] * (float)pa[k];
                v[8 + k] += taus[w] * (float)pb[k];
            }
        }
    }

    float s = 0.f, ss = 0.f;
#pragma unroll
    for (int k = 0; k < 16; ++k) { s += v[k]; ss += v[k] * v[k]; }
#pragma unroll
    for (int off = 1; off < 64; off <<= 1) {
        s  += __shfl_xor(s, off, 64);
        ss += __shfl_xor(ss, off, 64);
    }
    const float mu = s * (1.f / TD);
    const float var = ss * (1.f / TD) - mu * mu;
    const float r = rsqrtf(var + EPS);

#pragma unroll
    for (int q = 0; q < 4; ++q) {
        float4 g  = *(const float4*)(gamma + d0 + q * 4);
        float4 bt = *(const float4*)(beta + d0 + q * 4);
        float4 o;
        o.x = (v[q*4+0] - mu) * r * g.x + bt.x;
        o.y = (v[q*4+1] - mu) * r * g.y + bt.y;
        o.z = (v[q*4+2] - mu) * r * g.z + bt.z;
        o.w = (v[q*4+3] - mu) * r * g.w + bt.w;
        *(float4*)(out + (size_t)row * TD + d0 + q * 4) = o;
    }
}

// ---------------------------------------------------------------------------
extern "C" void kernel_launch(void* const* d_in, const int* in_sizes, int n_in,
                              void* d_out, int out_size, void* d_ws, size_t ws_size,
                              hipStream_t stream) {
    const float* x       = (const float*)d_in[0];
    const float* w1      = (const float*)d_in[1];
    const float* b1      = (const float*)d_in[2];
    const float* w2      = (const float*)d_in[3];
    const float* b2      = (const float*)d_in[4];
    const float* wv_w    = (const float*)d_in[5];
    const float* wv_b    = (const float*)d_in[6];
    const float* merge_w = (const float*)d_in[7];
    const float* merge_b = (const float*)d_in[8];
    const float* gamma   = (const float*)d_in[9];
    const float* beta    = (const float*)d_in[10];
    float* out = (float*)d_out;

    char* ws = (char*)d_ws;
    bf16*  Xbf   = (bf16*)ws;  ws += (size_t)TM * 1024 * 2;    // [8192][1024]
    bf16*  BigBT = (bf16*)ws;  ws += (size_t)CN * 1024 * 2;    // [3072 n][1024 k]
    bf16*  Amb   = (bf16*)ws;  ws += (size_t)1024 * 1024 * 2;  // merge_bot^T [j][e]
    bf16*  WvBf  = (bf16*)ws;  ws += (size_t)1024 * 1024 * 2;  // wv_w bf16
    float* cvecP = (float*)ws; ws += (size_t)4 * 1024 * 4;     // partials
    float* cvec  = (float*)ws; ws += (size_t)1024 * 4;         // wv_b @ merge_bot
    bf16*  Cbuf  = (bf16*)ws;                                  // [8192][3072]

    // 1. marshal everything (one launch)
    prep_kernel<<<12304, 256, 0, stream>>>(x, w1, wv_w, wv_b, merge_w,
                                           Xbf, BigBT, Amb, WvBf, cvecP);

    // 2. W' GEMM (full-GPU 64x64 tiles) + cvec reduction
    wprime_kernel<<<257, 256, 0, stream>>>(Amb, WvBf, BigBT + (size_t)1024 * 1024,
                                           cvecP, cvec);

    // 3. big GEMM: Cbuf = Xbf @ BigBT^T   (M=8192, N=3072, K=1024)
    gemm_big<<<dim3(32, 32), 256, 0, stream>>>(Xbf, BigBT, Cbuf);

    // 4. fused tau + combine + LayerNorm (wave-per-token, no barriers)
    final_kernel<<<TM / 4, 256, 0, stream>>>(Cbuf, b1, b2, w2, cvec, merge_b,
                                             gamma, beta, out);
}